// Round 7
// baseline (465.356 us; speedup 1.0000x reference)
//
#include <hip/hip_runtime.h>

#define HID 128
#define NODES 2032
#define NPT 127
#define NBLK 512

typedef _Float16 f16x8 __attribute__((ext_vector_type(8)));
typedef _Float16 f16x4 __attribute__((ext_vector_type(4)));
typedef _Float16 f16x2 __attribute__((ext_vector_type(2)));
typedef float f32x4 __attribute__((ext_vector_type(4)));

// post-order index (within one 127-node tree) of the p-th node at a level
// whose subtree size is sst = 2^(L+1)-1
__device__ __forceinline__ int tree_idx(int p, int sst) {
  return (p + 1) * sst + p - __popc(p) - 1;
}

// Leaves in p-order (lp = tree*64 + p) into level buffer 0, plus g-order fp32
// copy for the output kernel.
__global__ void leaf_kernel(const float* __restrict__ embed, const int* __restrict__ word_idx,
                            float* __restrict__ Hg, _Float16* __restrict__ H16,
                            float* __restrict__ H32) {
  int lp = blockIdx.x;                    // 0..1023
  int t = lp >> 6, p = lp & 63;
  int g = t * NPT + 2 * p - __popc(p);
  int wi = word_idx[g];
  const float2 e = ((const float2*)(embed + (size_t)wi * HID))[threadIdx.x];
  ((float2*)(Hg + (size_t)g * HID))[threadIdx.x] = e;
  ((float2*)(H32 + (size_t)lp * HID))[threadIdx.x] = e;
  f16x2 hv; hv[0] = (_Float16)e.x; hv[1] = (_Float16)e.y;
  ((f16x2*)(H16 + (size_t)lp * HID))[threadIdx.x] = hv;
}

__device__ __forceinline__ void grid_barrier(int* ctr, int nb) {
  __syncthreads();
  if (threadIdx.x == 0) {
    __hip_atomic_fetch_add(ctr, 1, __ATOMIC_ACQ_REL, __HIP_MEMORY_SCOPE_AGENT);
    while (__hip_atomic_load(ctr, __ATOMIC_RELAXED, __HIP_MEMORY_SCOPE_AGENT) < nb)
      __builtin_amdgcn_s_sleep(16);
    (void)__hip_atomic_load(ctr, __ATOMIC_ACQUIRE, __HIP_MEMORY_SCOPE_AGENT);
  }
  __syncthreads();
}

// Persistent fused kernel. Block = (h = bid>>2, kq = bid&3); V[h][64kq..][*] fp16
// in LDS (swizzled), staged once. Per level: per 64-node tile, stage the tile's
// children rows (contiguous 32 KB, p-order: c_n = rows 2n,2n+1) into LDS
// (swizzled), MFMA from LDS only, fp32 step-2 contraction + W-term -> per-block
// partial in pbuf[bid][n] (single-writer lines). Barrier A; combine phase
// partitioned BY NODE (block b owns row b: sums 4 kq partials + bias, tanh,
// writes contiguous H rows in fp16+fp32+g-order fp32). Barrier B; next level.
__global__ __launch_bounds__(256, 2) void fused_kernel(
    const float* __restrict__ V, const float* __restrict__ W, const float* __restrict__ bb,
    float* __restrict__ Hg,
    _Float16* __restrict__ H16a, float* __restrict__ H32a,
    _Float16* __restrict__ H16b, float* __restrict__ H32b,
    float* __restrict__ pbuf, int* __restrict__ syncb)
{
  __shared__ _Float16 Vlds[64 * 256];   // 32 KB
  __shared__ _Float16 Ct[64 * 256];     // 32 KB (64 nodes x 512 B c-rows)
  __shared__ float red[4][64];
  __shared__ float Wstrip[64];

  const int bid = blockIdx.x;
  const int h = bid >> 2, kq = bid & 3;
  const int tid = threadIdx.x;
  const int lane = tid & 63, w = tid >> 6;
  const int lo16 = lane & 15, q = lane >> 4;
  char* vb = (char*)Vlds;
  char* cb = (char*)Ct;

  // ---- stage V chunk: 64 rows x 256 cols fp32 -> fp16 LDS (swizzled)
  const float* Vsrc = V + ((size_t)h * 256 + (size_t)kq * 64) * 256;
#pragma unroll
  for (int it = 0; it < 16; ++it) {
    int idx = it * 256 + tid;            // float4 index, 4096 total
    int row = idx >> 6, c4 = idx & 63;
    float4 v = ((const float4*)Vsrc)[idx];
    f16x4 hv;
    hv[0] = (_Float16)v.x; hv[1] = (_Float16)v.y;
    hv[2] = (_Float16)v.z; hv[3] = (_Float16)v.w;
    int wa = (row * 512 + c4 * 8) ^ ((row & 7) << 4);
    *(f16x4*)(vb + wa) = hv;
  }
  if (tid < 64) Wstrip[tid] = W[(size_t)(kq * 64 + tid) * HID + h];

  float* myP = pbuf + (size_t)bid * 512;
  const _Float16* h16p = H16a; const float* h32p = H32a;
  _Float16* h16n = H16b;       float* h32n = H32b;

  for (int lv = 0; lv < 6; ++lv) {
    const int m = 512 >> lv;
    const int lognpt = 5 - lv;
    const int sst = (1 << (lv + 2)) - 1;
    const int ntiles = (m + 63) >> 6;

    for (int t = 0; t < ntiles; ++t) {
      const int n0 = t * 64;
      const int nn = (m - n0) > 64 ? 64 : (m - n0);
      const int ncf = nn >> 4;           // 4, 2, or 1

      __syncthreads();                   // protect Ct/V from previous readers
      // stage Ct: children rows 2n0 .. 2n0+2nn-1 (contiguous 512B*nn)
      const char* src = (const char*)h16p + (size_t)(2 * n0) * 256;
      const int units = nn * 32;         // 16B units
#pragma unroll
      for (int j = 0; j < 8; ++j) {
        int i = j * 256 + tid;
        if (i < units) {
          int r = i >> 5, c = i & 31;
          float4 d = *(const float4*)(src + (size_t)i * 16);
          int wa = (r * 512 + c * 16) ^ ((r & 7) << 4);
          *(float4*)(cb + wa) = d;
        }
      }
      __syncthreads();

      f32x4 acc[4];
#pragma unroll
      for (int cf = 0; cf < 4; ++cf) { f32x4 z = {0.f, 0.f, 0.f, 0.f}; acc[cf] = z; }

#pragma unroll
      for (int l0 = 0; l0 < 256; l0 += 32) {
        const int r = w * 16 + lo16;
        const f16x8 Af = *(const f16x8*)(vb + ((r * 512 + l0 * 2 + q * 16) ^ ((r & 7) << 4)));
#pragma unroll
        for (int cf = 0; cf < 4; ++cf) {
          if (cf < ncf) {
            const int nl = cf * 16 + lo16;
            const f16x8 Bf = *(const f16x8*)(cb + ((nl * 512 + l0 * 2 + q * 16) ^ ((nl & 7) << 4)));
            acc[cf] = __builtin_amdgcn_mfma_f32_16x16x32_f16(Af, Bf, acc[cf], 0, 0, 0);
          }
        }
      }

      // step-2: part[n] = sum_j c_n[k_j]*(T[k_j,n] + W[k_j,h]), fp32 c
      const int kk = kq * 64 + w * 16 + q * 4;      // global k of acc j=0
      const float ws0 = Wstrip[w * 16 + q * 4 + 0];
      const float ws1 = Wstrip[w * 16 + q * 4 + 1];
      const float ws2 = Wstrip[w * 16 + q * 4 + 2];
      const float ws3 = Wstrip[w * 16 + q * 4 + 3];
      float part[4];
#pragma unroll
      for (int cf = 0; cf < 4; ++cf) {
        part[cf] = 0.f;
        if (cf < ncf) {
          const int n = n0 + cf * 16 + lo16;
          const f32x4 cv = *(const f32x4*)(h32p + (size_t)(2 * n + (kk >> 7)) * HID + (kk & 127));
          part[cf] = cv[0] * (acc[cf][0] + ws0) + cv[1] * (acc[cf][1] + ws1)
                   + cv[2] * (acc[cf][2] + ws2) + cv[3] * (acc[cf][3] + ws3);
        }
      }
#pragma unroll
      for (int cf = 0; cf < 4; ++cf) {
        part[cf] += __shfl_xor(part[cf], 16);
        part[cf] += __shfl_xor(part[cf], 32);
      }
      if (q == 0) {
#pragma unroll
        for (int cf = 0; cf < 4; ++cf)
          if (cf < ncf) red[w][cf * 16 + lo16] = part[cf];
      }
      __syncthreads();
      if (w == 0 && lane < nn)
        myP[n0 + lane] = red[0][lane] + red[1][lane] + red[2][lane] + red[3][lane];
    }

    grid_barrier(syncb + lv * 64, NBLK);            // partials visible

    // combine phase: block b owns node-row b (single-writer contiguous rows)
    if (bid < m && tid < HID) {
      const int hh = tid;
      float s = pbuf[(size_t)(hh * 4 + 0) * 512 + bid]
              + pbuf[(size_t)(hh * 4 + 1) * 512 + bid]
              + pbuf[(size_t)(hh * 4 + 2) * 512 + bid]
              + pbuf[(size_t)(hh * 4 + 3) * 512 + bid] + bb[hh];
      float tnh = tanhf(s);
      h16n[(size_t)bid * HID + hh] = (_Float16)tnh;
      h32n[(size_t)bid * HID + hh] = tnh;
      const int tr = bid >> lognpt, p = bid & ((1 << lognpt) - 1);
      const int g = tr * NPT + tree_idx(p, sst);
      Hg[(size_t)g * HID + hh] = tnh;
    }

    if (lv < 5) grid_barrier(syncb + (6 + lv) * 64, NBLK);   // H rows visible

    { const _Float16* t16 = h16p; h16p = h16n; h16n = (_Float16*)t16; }
    { const float* t32 = h32p; h32p = h32n; h32n = (float*)t32; }
  }
}

__global__ void out_kernel(const float* __restrict__ Hg, const float* __restrict__ Wout,
                           const float* __restrict__ Wb, float* __restrict__ out) {
  int n = blockIdx.x * blockDim.x + threadIdx.x;
  if (n >= NODES) return;
  const float* hrow = Hg + (size_t)n * HID;
  float lg0 = Wb[0], lg1 = Wb[1], lg2 = Wb[2], lg3 = Wb[3], lg4 = Wb[4];
#pragma unroll
  for (int j = 0; j < 32; ++j) {
    float4 hv = ((const float4*)hrow)[j];
    const float* wr = Wout + (size_t)(j * 4) * 5;
    lg0 += hv.x * wr[0] + hv.y * wr[5] + hv.z * wr[10] + hv.w * wr[15];
    lg1 += hv.x * wr[1] + hv.y * wr[6] + hv.z * wr[11] + hv.w * wr[16];
    lg2 += hv.x * wr[2] + hv.y * wr[7] + hv.z * wr[12] + hv.w * wr[17];
    lg3 += hv.x * wr[3] + hv.y * wr[8] + hv.z * wr[13] + hv.w * wr[18];
    lg4 += hv.x * wr[4] + hv.y * wr[9] + hv.z * wr[14] + hv.w * wr[19];
  }
  float mm = fmaxf(fmaxf(fmaxf(lg0, lg1), fmaxf(lg2, lg3)), lg4);
  float ss = expf(lg0 - mm) + expf(lg1 - mm) + expf(lg2 - mm) + expf(lg3 - mm) + expf(lg4 - mm);
  float lse = mm + logf(ss);
  float* o = out + (size_t)n * 5;
  o[0] = lg0 - lse; o[1] = lg1 - lse; o[2] = lg2 - lse; o[3] = lg3 - lse; o[4] = lg4 - lse;
}

extern "C" void kernel_launch(void* const* d_in, const int* in_sizes, int n_in,
                              void* d_out, int out_size, void* d_ws, size_t ws_size,
                              hipStream_t stream) {
  const float* embed = (const float*)d_in[0];
  const float* V     = (const float*)d_in[1];
  const float* W     = (const float*)d_in[2];
  const float* b     = (const float*)d_in[3];
  const float* Wout  = (const float*)d_in[4];
  const float* Woutb = (const float*)d_in[5];
  // d_in[6..9] = is_leaf / word_idx / left / right; tree structure is implicit
  const int* word_idx = (const int*)d_in[7];
  float* out = (float*)d_out;

  // ws layout (16B-aligned): Hg | H16a | H16b | H32a | H32b | pbuf | sync
  char* wsb = (char*)d_ws;
  float*    Hg   = (float*)wsb;                       // 2032*128*4  = 1040384
  _Float16* H16a = (_Float16*)(wsb + 1040384);        // 1024*128*2  =  262144
  _Float16* H16b = (_Float16*)(wsb + 1302528);        //                262144
  float*    H32a = (float*)(wsb + 1564672);           // 1024*128*4  =  524288
  float*    H32b = (float*)(wsb + 2088960);           //                524288
  float*    pbuf = (float*)(wsb + 2613248);           // 512*512*4   = 1048576
  int*     syncb = (int*)(wsb + 3661824);             //                  4096

  hipMemsetAsync(syncb, 0, 4096, stream);
  leaf_kernel<<<1024, 64, 0, stream>>>(embed, word_idx, Hg, H16a, H32a);
  fused_kernel<<<NBLK, 256, 0, stream>>>(V, W, b, Hg, H16a, H32a, H16b, H32b, pbuf, syncb);
  out_kernel<<<(NODES + 255) / 256, 256, 0, stream>>>(Hg, Wout, Woutb, out);
}

// Round 9
// 104.844 us; speedup vs baseline: 4.4386x; 4.4386x over previous
//
#include <hip/hip_runtime.h>

#define HID 128
#define NODES 2032
#define NPT 127
#define NW 1024          // H16t row width (max nodes per level's child count)

typedef _Float16 f16x8 __attribute__((ext_vector_type(8)));
typedef _Float16 f16x4 __attribute__((ext_vector_type(4)));
typedef float f32x4 __attribute__((ext_vector_type(4)));

// post-order index (within one 127-node tree) of the p-th node at a level
// whose subtree size is sst = 2^(L+1)-1
__device__ __forceinline__ int tree_idx(int p, int sst) {
  return (p + 1) * sst + p - __popc(p) - 1;
}
// swizzled byte address in a [32][256] fp16 tile with 512B rows:
// XOR bits [8:4] of the column byte with (row&31) -> conflict-spread 16B units
__device__ __forceinline__ int cswz(int row, int colbyte) {
  return row * 512 + (colbyte ^ ((row & 31) << 4));
}

// one-time V fp32 -> fp16 (plain row-major [h][k][l])
// V = 8,388,608 floats = 2,097,152 float4 units = 1024 blocks x 256 thr x 8 it
__global__ void vconv_kernel(const float* __restrict__ V, _Float16* __restrict__ V16) {
  const int base = blockIdx.x * 2048 + threadIdx.x;
#pragma unroll
  for (int it = 0; it < 8; ++it) {
    const int i = base + it * 256;              // float4 unit, 2097152 total
    const float4 v = ((const float4*)V)[i];
    f16x4 o;
    o[0] = (_Float16)v.x; o[1] = (_Float16)v.y;
    o[2] = (_Float16)v.z; o[3] = (_Float16)v.w;
    ((f16x4*)V16)[i] = o;
  }
}

// leaves: block h (128 blocks), thread loops 4 leaves; writes transposed rows
__global__ void leaf_kernel(const float* __restrict__ embed, const int* __restrict__ word_idx,
                            _Float16* __restrict__ H16, float* __restrict__ Hgt) {
  const int h = blockIdx.x;
#pragma unroll
  for (int it = 0; it < 4; ++it) {
    const int lp = it * 256 + threadIdx.x;      // 0..1023
    const int t = lp >> 6, p = lp & 63;
    const int g = t * NPT + 2 * p - __popc(p);
    const int wi = word_idx[g];
    const float e = embed[(size_t)wi * HID + h];
    H16[(size_t)h * NW + lp] = (_Float16)e;
    Hgt[(size_t)h * 2048 + g] = e;
  }
}

// Level kernel: block = (h, node-part). 4 waves; wave w owns k-strip [64w,64w+64).
// A (V16[h], 64x256 fp16 per wave) prefetched into 128 VGPRs with 32 independent
// 16B loads (deep queue). Per 32-node tile: stage children (contig cols 2n,2n+1 of
// H16t) into swizzled LDS, MFMA from regs x LDS, step-2 contraction with fp16 c
// from the same LDS tile + fused W-column term, block-local k-reduction, tanh,
// single-writer transposed H writes. No cross-block sync of any kind.
template<int NSPL>
__global__ __launch_bounds__(256, 2) void level_kernel(
    const _Float16* __restrict__ V16, const float* __restrict__ W, const float* __restrict__ bb,
    const _Float16* __restrict__ Hp, _Float16* __restrict__ Hn,
    float* __restrict__ Hgt, int lv)
{
  __shared__ _Float16 Ct[32 * 256];   // 16 KB, swizzled
  __shared__ float Wk[256];
  __shared__ float red[4][32];

  const int bid = blockIdx.x;
  const int h = bid / NSPL, part = bid % NSPL;
  const int tid = threadIdx.x, lane = tid & 63, w = tid >> 6;
  const int lo16 = lane & 15, q = lane >> 4;

  const int m = 512 >> lv;
  const int lognpt = 5 - lv;
  const int sst = (1 << (lv + 2)) - 1;
  const int nodes_blk = m / NSPL;
  const int n_start = part * nodes_blk;
  const int ntiles = (nodes_blk + 31) >> 5;

  Wk[tid] = W[(size_t)tid * HID + h];

  // ---- A prefetch: whole k-strip into registers (32 independent 16B loads)
  const _Float16* Vh = V16 + (size_t)h * 65536;
  f16x8 af[4][8];
#pragma unroll
  for (int rf = 0; rf < 4; ++rf) {
    const int r = w * 64 + rf * 16 + lo16;
#pragma unroll
    for (int lc = 0; lc < 8; ++lc)
      af[rf][lc] = *(const f16x8*)(Vh + (size_t)r * 256 + lc * 32 + q * 8);
  }
  __syncthreads();
  f32x4 wk[4];
#pragma unroll
  for (int rf = 0; rf < 4; ++rf)
    wk[rf] = *(const f32x4*)&Wk[w * 64 + rf * 16 + q * 4];
  const float bh = bb[h];
  char* cb = (char*)Ct;

  for (int t = 0; t < ntiles; ++t) {
    const int nb = n_start + t * 32;
    int nn = nodes_blk - t * 32; if (nn > 32) nn = 32;
    const int ncf = (nn + 15) >> 4;

    __syncthreads();                  // previous tile's LDS reads complete
    {                                  // ---- C-tile stage (coalesced + deinterleave)
      const int nidx = tid & 31, oct = tid >> 5;
      if (nidx < nn) {
#pragma unroll
        for (int half = 0; half < 2; ++half) {
          unsigned int u[8];
#pragma unroll
          for (int j = 0; j < 8; ++j)
            u[j] = *(const unsigned int*)(Hp + (size_t)(half * 64 + oct * 8 + j) * NW + 2 * (nb + nidx));
          union { f16x8 v; unsigned short s[8]; } a0, a1;
#pragma unroll
          for (int j = 0; j < 8; ++j) {
            a0.s[j] = (unsigned short)(u[j] & 0xffffu);
            a1.s[j] = (unsigned short)(u[j] >> 16);
          }
          *(f16x8*)(cb + cswz(nidx, half * 128 + oct * 16)) = a0.v;        // child0: l in [0,128)
          *(f16x8*)(cb + cswz(nidx, 256 + half * 128 + oct * 16)) = a1.v;  // child1: l in [128,256)
        }
      }
    }
    __syncthreads();

    f32x4 acc[4][2];
#pragma unroll
    for (int rf = 0; rf < 4; ++rf)
#pragma unroll
      for (int cf = 0; cf < 2; ++cf) { f32x4 z = {0.f, 0.f, 0.f, 0.f}; acc[rf][cf] = z; }

#pragma unroll
    for (int lc = 0; lc < 8; ++lc) {
#pragma unroll
      for (int cf = 0; cf < 2; ++cf) {
        if (cf < ncf) {
          const int nl = cf * 16 + lo16;
          const f16x8 Bf = *(const f16x8*)(cb + cswz(nl, lc * 64 + q * 16));
#pragma unroll
          for (int rf = 0; rf < 4; ++rf)
            acc[rf][cf] = __builtin_amdgcn_mfma_f32_16x16x32_f16(af[rf][lc], Bf, acc[rf][cf], 0, 0, 0);
        }
      }
    }

    // ---- step-2: part[n] = sum_k c_n[k]*(T[k,n] + W[k,h]); c fp16 from LDS
    float pt[2];
#pragma unroll
    for (int cf = 0; cf < 2; ++cf) {
      pt[cf] = 0.f;
      if (cf < ncf) {
        const int nl = cf * 16 + lo16;
        float s = 0.f;
#pragma unroll
        for (int rf = 0; rf < 4; ++rf) {
          const int kb = w * 64 + rf * 16 + q * 4;
          const f16x4 cv = *(const f16x4*)(cb + cswz(nl, kb * 2));
          s += (float)cv[0] * (acc[rf][cf][0] + wk[rf][0])
             + (float)cv[1] * (acc[rf][cf][1] + wk[rf][1])
             + (float)cv[2] * (acc[rf][cf][2] + wk[rf][2])
             + (float)cv[3] * (acc[rf][cf][3] + wk[rf][3]);
        }
        pt[cf] = s;
      }
    }
#pragma unroll
    for (int cf = 0; cf < 2; ++cf) {
      pt[cf] += __shfl_xor(pt[cf], 16);
      pt[cf] += __shfl_xor(pt[cf], 32);
    }
    if (q == 0) {
#pragma unroll
      for (int cf = 0; cf < 2; ++cf)
        if (cf < ncf) red[w][cf * 16 + lo16] = pt[cf];
    }
    __syncthreads();
    if (tid < nn) {
      const float x = red[0][tid] + red[1][tid] + red[2][tid] + red[3][tid] + bh;
      const float tnh = tanhf(x);
      const int node = nb + tid;
      Hn[(size_t)h * NW + node] = (_Float16)tnh;
      const int tr = node >> lognpt, p = node & ((1 << lognpt) - 1);
      const int g = tr * NPT + tree_idx(p, sst);
      Hgt[(size_t)h * 2048 + g] = tnh;
    }
  }
}

// out: lane = node (g-order), reads Hgt columns coalesced across lanes
__global__ void out_kernel(const float* __restrict__ Hgt, const float* __restrict__ Wout,
                           const float* __restrict__ Wb, float* __restrict__ out) {
  const int n = blockIdx.x * blockDim.x + threadIdx.x;
  if (n >= NODES) return;
  float lg0 = Wb[0], lg1 = Wb[1], lg2 = Wb[2], lg3 = Wb[3], lg4 = Wb[4];
#pragma unroll 4
  for (int h = 0; h < HID; ++h) {
    const float x = Hgt[(size_t)h * 2048 + n];
    const float* wr = Wout + (size_t)h * 5;
    lg0 += x * wr[0]; lg1 += x * wr[1]; lg2 += x * wr[2];
    lg3 += x * wr[3]; lg4 += x * wr[4];
  }
  const float mm = fmaxf(fmaxf(fmaxf(lg0, lg1), fmaxf(lg2, lg3)), lg4);
  const float ss = expf(lg0 - mm) + expf(lg1 - mm) + expf(lg2 - mm)
                 + expf(lg3 - mm) + expf(lg4 - mm);
  const float lse = mm + logf(ss);
  float* o = out + (size_t)n * 5;
  o[0] = lg0 - lse; o[1] = lg1 - lse; o[2] = lg2 - lse; o[3] = lg3 - lse; o[4] = lg4 - lse;
}

extern "C" void kernel_launch(void* const* d_in, const int* in_sizes, int n_in,
                              void* d_out, int out_size, void* d_ws, size_t ws_size,
                              hipStream_t stream) {
  const float* embed = (const float*)d_in[0];
  const float* V     = (const float*)d_in[1];
  const float* W     = (const float*)d_in[2];
  const float* b     = (const float*)d_in[3];
  const float* Wout  = (const float*)d_in[4];
  const float* Woutb = (const float*)d_in[5];
  // d_in[6..9]: is_leaf/left/right are structural (implicit); word_idx used
  const int* word_idx = (const int*)d_in[7];
  float* out = (float*)d_out;

  // ws: V16 | H16A | H16B | Hgt
  char* wsb = (char*)d_ws;
  _Float16* V16  = (_Float16*)wsb;                      // 128*256*256*2 = 16777216
  _Float16* H16A = (_Float16*)(wsb + 16777216);         // 128*1024*2    =   262144
  _Float16* H16B = (_Float16*)(wsb + 17039360);         //                  262144
  float*    Hgt  = (float*)(wsb + 17301504);            // 128*2048*4    =  1048576

  vconv_kernel<<<1024, 256, 0, stream>>>(V, V16);
  leaf_kernel<<<128, 256, 0, stream>>>(embed, word_idx, H16A, Hgt);

  level_kernel<2><<<256, 256, 0, stream>>>(V16, W, b, H16A, H16B, Hgt, 0); // m=512
  level_kernel<2><<<256, 256, 0, stream>>>(V16, W, b, H16B, H16A, Hgt, 1); // m=256
  level_kernel<2><<<256, 256, 0, stream>>>(V16, W, b, H16A, H16B, Hgt, 2); // m=128
  level_kernel<2><<<256, 256, 0, stream>>>(V16, W, b, H16B, H16A, Hgt, 3); // m=64
  level_kernel<2><<<256, 256, 0, stream>>>(V16, W, b, H16A, H16B, Hgt, 4); // m=32
  level_kernel<1><<<128, 256, 0, stream>>>(V16, W, b, H16B, H16A, Hgt, 5); // m=16

  out_kernel<<<8, 256, 0, stream>>>(Hgt, Wout, Woutb, out);
}

// Round 10
// 100.940 us; speedup vs baseline: 4.6102x; 1.0387x over previous
//
#include <hip/hip_runtime.h>

#define HID 128
#define NODES 2032
#define NPT 127
#define NW 1024          // H16t row width (max nodes per level's child count)

typedef _Float16 f16x8 __attribute__((ext_vector_type(8)));
typedef _Float16 f16x4 __attribute__((ext_vector_type(4)));
typedef float f32x4 __attribute__((ext_vector_type(4)));

// post-order index (within one 127-node tree) of the p-th node at a level
// whose subtree size is sst = 2^(L+1)-1
__device__ __forceinline__ int tree_idx(int p, int sst) {
  return (p + 1) * sst + p - __popc(p) - 1;
}
// swizzled byte address in a [32][256] fp16 tile with 512B rows:
// XOR bits [8:4] of the column byte with (row&31)<<4 -> conflict-spread 16B units
__device__ __forceinline__ int cswz(int row, int colbyte) {
  return row * 512 + (colbyte ^ ((row & 31) << 4));
}

// one-time V fp32 -> fp16 (plain row-major [h][k][l])
// V = 8,388,608 floats = 2,097,152 float4 units = 1024 blocks x 256 thr x 8 it
__global__ void vconv_kernel(const float* __restrict__ V, _Float16* __restrict__ V16) {
  const int base = blockIdx.x * 2048 + threadIdx.x;
#pragma unroll
  for (int it = 0; it < 8; ++it) {
    const int i = base + it * 256;
    const float4 v = ((const float4*)V)[i];
    f16x4 o;
    o[0] = (_Float16)v.x; o[1] = (_Float16)v.y;
    o[2] = (_Float16)v.z; o[3] = (_Float16)v.w;
    ((f16x4*)V16)[i] = o;
  }
}

// leaves: block h (128 blocks), thread loops 4 leaves; writes transposed rows
__global__ void leaf_kernel(const float* __restrict__ embed, const int* __restrict__ word_idx,
                            _Float16* __restrict__ H16, float* __restrict__ Hgt) {
  const int h = blockIdx.x;
#pragma unroll
  for (int it = 0; it < 4; ++it) {
    const int lp = it * 256 + threadIdx.x;      // 0..1023
    const int t = lp >> 6, p = lp & 63;
    const int g = t * NPT + 2 * p - __popc(p);
    const int wi = word_idx[g];
    const float e = embed[(size_t)wi * HID + h];
    H16[(size_t)h * NW + lp] = (_Float16)e;
    Hgt[(size_t)h * 2048 + g] = e;
  }
}

// Level kernel: block = (h, node-part). 4 waves; wave w owns k-strip [64w,64w+64).
// A (V16[h]) prefetched into 128 VGPRs (32 independent 16B loads). C-tiles are
// software-pipelined: issue tile t+1's global loads before computing tile t
// (T14 async-stage split), deinterleave+write into the other half of a
// double-buffered swizzled LDS tile after the epilogue, one barrier. MFMA from
// regs x LDS; fp32 step-2 contraction + fused W-column term; block-local
// k-reduction; tanh; single-writer transposed H writes. No cross-block sync.
template<int NSPL>
__global__ __launch_bounds__(256, 2) void level_kernel(
    const _Float16* __restrict__ V16, const float* __restrict__ W, const float* __restrict__ bb,
    const _Float16* __restrict__ Hp, _Float16* __restrict__ Hn,
    float* __restrict__ Hgt, int lv)
{
  __shared__ _Float16 Ct[2][32 * 256];   // 2 x 16 KB double-buffer, swizzled
  __shared__ float Wk[256];
  __shared__ float red[4][32];

  const int bid = blockIdx.x;
  const int h = bid / NSPL, part = bid % NSPL;
  const int tid = threadIdx.x, lane = tid & 63, w = tid >> 6;
  const int lo16 = lane & 15, q = lane >> 4;
  const int nidx = tid & 31, oct = tid >> 5;

  const int m = 512 >> lv;
  const int lognpt = 5 - lv;
  const int sst = (1 << (lv + 2)) - 1;
  const int nodes_blk = m / NSPL;
  const int n_start = part * nodes_blk;
  const int ntiles = (nodes_blk + 31) >> 5;

  Wk[tid] = W[(size_t)tid * HID + h];

  // ---- tile-0 C loads issued FIRST (so vmcnt-wait on them doesn't drain A)
  unsigned int nxt[16];
  {
    const int nn0 = nodes_blk > 32 ? 32 : nodes_blk;
    if (nidx < nn0) {
#pragma unroll
      for (int half = 0; half < 2; ++half)
#pragma unroll
        for (int j = 0; j < 8; ++j)
          nxt[half * 8 + j] = *(const unsigned int*)(
              Hp + (size_t)(half * 64 + oct * 8 + j) * NW + 2 * (n_start + nidx));
    }
  }

  // ---- A prefetch: whole k-strip into registers (32 independent 16B loads)
  const _Float16* Vh = V16 + (size_t)h * 65536;
  f16x8 af[4][8];
#pragma unroll
  for (int rf = 0; rf < 4; ++rf) {
    const int r = w * 64 + rf * 16 + lo16;
#pragma unroll
    for (int lc = 0; lc < 8; ++lc)
      af[rf][lc] = *(const f16x8*)(Vh + (size_t)r * 256 + lc * 32 + q * 8);
  }

  // ---- write tile 0 into buffer 0 (compiler waits vmcnt for nxt only)
  {
    const int nn0 = nodes_blk > 32 ? 32 : nodes_blk;
    if (nidx < nn0) {
      char* cb0 = (char*)Ct[0];
#pragma unroll
      for (int half = 0; half < 2; ++half) {
        union { f16x8 v; unsigned short s[8]; } a0, a1;
#pragma unroll
        for (int j = 0; j < 8; ++j) {
          a0.s[j] = (unsigned short)(nxt[half * 8 + j] & 0xffffu);
          a1.s[j] = (unsigned short)(nxt[half * 8 + j] >> 16);
        }
        *(f16x8*)(cb0 + cswz(nidx, half * 128 + oct * 16)) = a0.v;
        *(f16x8*)(cb0 + cswz(nidx, 256 + half * 128 + oct * 16)) = a1.v;
      }
    }
  }
  __syncthreads();

  f32x4 wk[4];
#pragma unroll
  for (int rf = 0; rf < 4; ++rf)
    wk[rf] = *(const f32x4*)&Wk[w * 64 + rf * 16 + q * 4];
  const float bh = bb[h];

  int cur = 0;
  for (int t = 0; t < ntiles; ++t) {
    const int nb = n_start + t * 32;
    int nn = nodes_blk - t * 32; if (nn > 32) nn = 32;
    const int ncf = (nn + 15) >> 4;
    char* cb = (char*)Ct[cur];

    // ---- issue next tile's loads (latency hides under MFMA + step-2)
    int nnn = nodes_blk - (t + 1) * 32; if (nnn > 32) nnn = 32;
    if (t + 1 < ntiles && nidx < nnn) {
#pragma unroll
      for (int half = 0; half < 2; ++half)
#pragma unroll
        for (int j = 0; j < 8; ++j)
          nxt[half * 8 + j] = *(const unsigned int*)(
              Hp + (size_t)(half * 64 + oct * 8 + j) * NW + 2 * (nb + 32 + nidx));
    }

    f32x4 acc[4][2];
#pragma unroll
    for (int rf = 0; rf < 4; ++rf)
#pragma unroll
      for (int cf = 0; cf < 2; ++cf) { f32x4 z = {0.f, 0.f, 0.f, 0.f}; acc[rf][cf] = z; }

#pragma unroll
    for (int lc = 0; lc < 8; ++lc) {
#pragma unroll
      for (int cf = 0; cf < 2; ++cf) {
        if (cf < ncf) {
          const int nl = cf * 16 + lo16;
          const f16x8 Bf = *(const f16x8*)(cb + cswz(nl, lc * 64 + q * 16));
#pragma unroll
          for (int rf = 0; rf < 4; ++rf)
            acc[rf][cf] = __builtin_amdgcn_mfma_f32_16x16x32_f16(af[rf][lc], Bf, acc[rf][cf], 0, 0, 0);
        }
      }
    }

    // ---- step-2: part[n] = sum_k c_n[k]*(T[k,n] + W[k,h]); c fp16 from LDS
    float pt[2];
#pragma unroll
    for (int cf = 0; cf < 2; ++cf) {
      pt[cf] = 0.f;
      if (cf < ncf) {
        const int nl = cf * 16 + lo16;
        float s = 0.f;
#pragma unroll
        for (int rf = 0; rf < 4; ++rf) {
          const int kb = w * 64 + rf * 16 + q * 4;
          const f16x4 cv = *(const f16x4*)(cb + cswz(nl, kb * 2));
          s += (float)cv[0] * (acc[rf][cf][0] + wk[rf][0])
             + (float)cv[1] * (acc[rf][cf][1] + wk[rf][1])
             + (float)cv[2] * (acc[rf][cf][2] + wk[rf][2])
             + (float)cv[3] * (acc[rf][cf][3] + wk[rf][3]);
        }
        pt[cf] = s;
      }
    }
#pragma unroll
    for (int cf = 0; cf < 2; ++cf) {
      pt[cf] += __shfl_xor(pt[cf], 16);
      pt[cf] += __shfl_xor(pt[cf], 32);
    }
    if (q == 0) {
#pragma unroll
      for (int cf = 0; cf < 2; ++cf)
        if (cf < ncf) red[w][cf * 16 + lo16] = pt[cf];
    }
    __syncthreads();

    // ---- epilogue
    if (tid < nn) {
      const float x = red[0][tid] + red[1][tid] + red[2][tid] + red[3][tid] + bh;
      const float tnh = tanhf(x);
      const int node = nb + tid;
      Hn[(size_t)h * NW + node] = (_Float16)tnh;
      const int tr = node >> lognpt, p = node & ((1 << lognpt) - 1);
      const int g = tr * NPT + tree_idx(p, sst);
      Hgt[(size_t)h * 2048 + g] = tnh;
    }

    // ---- deinterleave + write next tile into the other buffer
    if (t + 1 < ntiles && nidx < nnn) {
      char* cbn = (char*)Ct[cur ^ 1];
#pragma unroll
      for (int half = 0; half < 2; ++half) {
        union { f16x8 v; unsigned short s[8]; } a0, a1;
#pragma unroll
        for (int j = 0; j < 8; ++j) {
          a0.s[j] = (unsigned short)(nxt[half * 8 + j] & 0xffffu);
          a1.s[j] = (unsigned short)(nxt[half * 8 + j] >> 16);
        }
        *(f16x8*)(cbn + cswz(nidx, half * 128 + oct * 16)) = a0.v;
        *(f16x8*)(cbn + cswz(nidx, 256 + half * 128 + oct * 16)) = a1.v;
      }
    }
    __syncthreads();
    cur ^= 1;
  }
}

// out: lane = node (g-order), reads Hgt columns coalesced across lanes
__global__ void out_kernel(const float* __restrict__ Hgt, const float* __restrict__ Wout,
                           const float* __restrict__ Wb, float* __restrict__ out) {
  const int n = blockIdx.x * blockDim.x + threadIdx.x;
  if (n >= NODES) return;
  float lg0 = Wb[0], lg1 = Wb[1], lg2 = Wb[2], lg3 = Wb[3], lg4 = Wb[4];
#pragma unroll 4
  for (int h = 0; h < HID; ++h) {
    const float x = Hgt[(size_t)h * 2048 + n];
    const float* wr = Wout + (size_t)h * 5;
    lg0 += x * wr[0]; lg1 += x * wr[1]; lg2 += x * wr[2];
    lg3 += x * wr[3]; lg4 += x * wr[4];
  }
  const float mm = fmaxf(fmaxf(fmaxf(lg0, lg1), fmaxf(lg2, lg3)), lg4);
  const float ss = expf(lg0 - mm) + expf(lg1 - mm) + expf(lg2 - mm)
                 + expf(lg3 - mm) + expf(lg4 - mm);
  const float lse = mm + logf(ss);
  float* o = out + (size_t)n * 5;
  o[0] = lg0 - lse; o[1] = lg1 - lse; o[2] = lg2 - lse; o[3] = lg3 - lse; o[4] = lg4 - lse;
}

extern "C" void kernel_launch(void* const* d_in, const int* in_sizes, int n_in,
                              void* d_out, int out_size, void* d_ws, size_t ws_size,
                              hipStream_t stream) {
  const float* embed = (const float*)d_in[0];
  const float* V     = (const float*)d_in[1];
  const float* W     = (const float*)d_in[2];
  const float* b     = (const float*)d_in[3];
  const float* Wout  = (const float*)d_in[4];
  const float* Woutb = (const float*)d_in[5];
  // d_in[6..9]: is_leaf/left/right are structural (implicit); word_idx used
  const int* word_idx = (const int*)d_in[7];
  float* out = (float*)d_out;

  // ws: V16 | H16A | H16B | Hgt
  char* wsb = (char*)d_ws;
  _Float16* V16  = (_Float16*)wsb;                      // 128*256*256*2 = 16777216
  _Float16* H16A = (_Float16*)(wsb + 16777216);         // 128*1024*2    =   262144
  _Float16* H16B = (_Float16*)(wsb + 17039360);         //                  262144
  float*    Hgt  = (float*)(wsb + 17301504);            // 128*2048*4    =  1048576

  vconv_kernel<<<1024, 256, 0, stream>>>(V, V16);
  leaf_kernel<<<128, 256, 0, stream>>>(embed, word_idx, H16A, Hgt);

  level_kernel<4><<<512, 256, 0, stream>>>(V16, W, b, H16A, H16B, Hgt, 0); // m=512, 4 tiles
  level_kernel<4><<<512, 256, 0, stream>>>(V16, W, b, H16B, H16A, Hgt, 1); // m=256, 2 tiles
  level_kernel<2><<<256, 256, 0, stream>>>(V16, W, b, H16A, H16B, Hgt, 2); // m=128, 2 tiles
  level_kernel<2><<<256, 256, 0, stream>>>(V16, W, b, H16B, H16A, Hgt, 3); // m=64, 1 tile
  level_kernel<2><<<256, 256, 0, stream>>>(V16, W, b, H16A, H16B, Hgt, 4); // m=32, 1 tile
  level_kernel<1><<<128, 256, 0, stream>>>(V16, W, b, H16B, H16A, Hgt, 5); // m=16, 1 tile

  out_kernel<<<8, 256, 0, stream>>>(Hgt, Wout, Woutb, out);
}

// Round 11
// 100.770 us; speedup vs baseline: 4.6180x; 1.0017x over previous
//
#include <hip/hip_runtime.h>

#define HID 128
#define NODES 2032
#define NPT 127
#define NW 1024          // H16t row width

typedef _Float16 f16x8 __attribute__((ext_vector_type(8)));
typedef _Float16 f16x4 __attribute__((ext_vector_type(4)));
typedef float f32x4 __attribute__((ext_vector_type(4)));

// post-order index (within one 127-node tree) of the p-th node at a level
// whose subtree size is sst = 2^(L+1)-1
__device__ __forceinline__ int tree_idx(int p, int sst) {
  return (p + 1) * sst + p - __popc(p) - 1;
}
// swizzled byte address in a [32][256] fp16 tile with 512B rows
__device__ __forceinline__ int cswz(int row, int colbyte) {
  return row * 512 + (colbyte ^ ((row & 31) << 4));
}

// prep: blocks 0..1023 convert V fp32->fp16; blocks 1024..1151 do leaves
__global__ void prep_kernel(const float* __restrict__ V, _Float16* __restrict__ V16,
                            const float* __restrict__ embed, const int* __restrict__ word_idx,
                            _Float16* __restrict__ H16, float* __restrict__ Hgt) {
  const int b = blockIdx.x;
  if (b < 1024) {
    const int base = b * 2048 + threadIdx.x;
#pragma unroll
    for (int it = 0; it < 8; ++it) {
      const int i = base + it * 256;            // float4 unit, 2097152 total
      const float4 v = ((const float4*)V)[i];
      f16x4 o;
      o[0] = (_Float16)v.x; o[1] = (_Float16)v.y;
      o[2] = (_Float16)v.z; o[3] = (_Float16)v.w;
      ((f16x4*)V16)[i] = o;
    }
  } else {
    const int h = b - 1024;
#pragma unroll
    for (int it = 0; it < 4; ++it) {
      const int lp = it * 256 + threadIdx.x;    // 0..1023
      const int t = lp >> 6, p = lp & 63;
      const int g = t * NPT + 2 * p - __popc(p);
      const int wi = word_idx[g];
      const float e = embed[(size_t)wi * HID + h];
      H16[(size_t)h * NW + lp] = (_Float16)e;
      Hgt[(size_t)h * 2048 + g] = e;
    }
  }
}

// Big-level kernel (lv0-2): R10 design — block=(h,part), A in 128 VGPRs,
// double-buffered pipelined C-tiles, fused W-term, transposed single-writer H.
template<int NSPL>
__global__ __launch_bounds__(256, 2) void level_kernel(
    const _Float16* __restrict__ V16, const float* __restrict__ W, const float* __restrict__ bb,
    const _Float16* __restrict__ Hp, _Float16* __restrict__ Hn,
    float* __restrict__ Hgt, int lv)
{
  __shared__ _Float16 Ct[2][32 * 256];
  __shared__ float Wk[256];
  __shared__ float red[4][32];

  const int bid = blockIdx.x;
  const int h = bid / NSPL, part = bid % NSPL;
  const int tid = threadIdx.x, lane = tid & 63, w = tid >> 6;
  const int lo16 = lane & 15, q = lane >> 4;
  const int nidx = tid & 31, oct = tid >> 5;

  const int m = 512 >> lv;
  const int lognpt = 5 - lv;
  const int sst = (1 << (lv + 2)) - 1;
  const int nodes_blk = m / NSPL;
  const int n_start = part * nodes_blk;
  const int ntiles = (nodes_blk + 31) >> 5;

  Wk[tid] = W[(size_t)tid * HID + h];

  unsigned int nxt[16];
  {
    const int nn0 = nodes_blk > 32 ? 32 : nodes_blk;
    if (nidx < nn0) {
#pragma unroll
      for (int half = 0; half < 2; ++half)
#pragma unroll
        for (int j = 0; j < 8; ++j)
          nxt[half * 8 + j] = *(const unsigned int*)(
              Hp + (size_t)(half * 64 + oct * 8 + j) * NW + 2 * (n_start + nidx));
    }
  }

  const _Float16* Vh = V16 + (size_t)h * 65536;
  f16x8 af[4][8];
#pragma unroll
  for (int rf = 0; rf < 4; ++rf) {
    const int r = w * 64 + rf * 16 + lo16;
#pragma unroll
    for (int lc = 0; lc < 8; ++lc)
      af[rf][lc] = *(const f16x8*)(Vh + (size_t)r * 256 + lc * 32 + q * 8);
  }

  {
    const int nn0 = nodes_blk > 32 ? 32 : nodes_blk;
    if (nidx < nn0) {
      char* cb0 = (char*)Ct[0];
#pragma unroll
      for (int half = 0; half < 2; ++half) {
        union { f16x8 v; unsigned short s[8]; } a0, a1;
#pragma unroll
        for (int j = 0; j < 8; ++j) {
          a0.s[j] = (unsigned short)(nxt[half * 8 + j] & 0xffffu);
          a1.s[j] = (unsigned short)(nxt[half * 8 + j] >> 16);
        }
        *(f16x8*)(cb0 + cswz(nidx, half * 128 + oct * 16)) = a0.v;
        *(f16x8*)(cb0 + cswz(nidx, 256 + half * 128 + oct * 16)) = a1.v;
      }
    }
  }
  __syncthreads();

  f32x4 wk[4];
#pragma unroll
  for (int rf = 0; rf < 4; ++rf)
    wk[rf] = *(const f32x4*)&Wk[w * 64 + rf * 16 + q * 4];
  const float bh = bb[h];

  int cur = 0;
  for (int t = 0; t < ntiles; ++t) {
    const int nb = n_start + t * 32;
    int nn = nodes_blk - t * 32; if (nn > 32) nn = 32;
    const int ncf = (nn + 15) >> 4;
    char* cb = (char*)Ct[cur];

    int nnn = nodes_blk - (t + 1) * 32; if (nnn > 32) nnn = 32;
    if (t + 1 < ntiles && nidx < nnn) {
#pragma unroll
      for (int half = 0; half < 2; ++half)
#pragma unroll
        for (int j = 0; j < 8; ++j)
          nxt[half * 8 + j] = *(const unsigned int*)(
              Hp + (size_t)(half * 64 + oct * 8 + j) * NW + 2 * (nb + 32 + nidx));
    }

    f32x4 acc[4][2];
#pragma unroll
    for (int rf = 0; rf < 4; ++rf)
#pragma unroll
      for (int cf = 0; cf < 2; ++cf) { f32x4 z = {0.f, 0.f, 0.f, 0.f}; acc[rf][cf] = z; }

#pragma unroll
    for (int lc = 0; lc < 8; ++lc) {
#pragma unroll
      for (int cf = 0; cf < 2; ++cf) {
        if (cf < ncf) {
          const int nl = cf * 16 + lo16;
          const f16x8 Bf = *(const f16x8*)(cb + cswz(nl, lc * 64 + q * 16));
#pragma unroll
          for (int rf = 0; rf < 4; ++rf)
            acc[rf][cf] = __builtin_amdgcn_mfma_f32_16x16x32_f16(af[rf][lc], Bf, acc[rf][cf], 0, 0, 0);
        }
      }
    }

    float pt[2];
#pragma unroll
    for (int cf = 0; cf < 2; ++cf) {
      pt[cf] = 0.f;
      if (cf < ncf) {
        const int nl = cf * 16 + lo16;
        float s = 0.f;
#pragma unroll
        for (int rf = 0; rf < 4; ++rf) {
          const int kb = w * 64 + rf * 16 + q * 4;
          const f16x4 cv = *(const f16x4*)(cb + cswz(nl, kb * 2));
          s += (float)cv[0] * (acc[rf][cf][0] + wk[rf][0])
             + (float)cv[1] * (acc[rf][cf][1] + wk[rf][1])
             + (float)cv[2] * (acc[rf][cf][2] + wk[rf][2])
             + (float)cv[3] * (acc[rf][cf][3] + wk[rf][3]);
        }
        pt[cf] = s;
      }
    }
#pragma unroll
    for (int cf = 0; cf < 2; ++cf) {
      pt[cf] += __shfl_xor(pt[cf], 16);
      pt[cf] += __shfl_xor(pt[cf], 32);
    }
    if (q == 0) {
#pragma unroll
      for (int cf = 0; cf < 2; ++cf)
        if (cf < ncf) red[w][cf * 16 + lo16] = pt[cf];
    }
    __syncthreads();

    if (tid < nn) {
      const float x = red[0][tid] + red[1][tid] + red[2][tid] + red[3][tid] + bh;
      const float tnh = tanhf(x);
      const int node = nb + tid;
      Hn[(size_t)h * NW + node] = (_Float16)tnh;
      const int tr = node >> lognpt, p = node & ((1 << lognpt) - 1);
      const int g = tr * NPT + tree_idx(p, sst);
      Hgt[(size_t)h * 2048 + g] = tnh;
    }

    if (t + 1 < ntiles && nidx < nnn) {
      char* cbn = (char*)Ct[cur ^ 1];
#pragma unroll
      for (int half = 0; half < 2; ++half) {
        union { f16x8 v; unsigned short s[8]; } a0, a1;
#pragma unroll
        for (int j = 0; j < 8; ++j) {
          a0.s[j] = (unsigned short)(nxt[half * 8 + j] & 0xffffu);
          a1.s[j] = (unsigned short)(nxt[half * 8 + j] >> 16);
        }
        *(f16x8*)(cbn + cswz(nidx, half * 128 + oct * 16)) = a0.v;
        *(f16x8*)(cbn + cswz(nidx, 256 + half * 128 + oct * 16)) = a1.v;
      }
    }
    __syncthreads();
    cur ^= 1;
  }
}

// hierarchical grid barrier for 128 blocks: 8 group counters (64B apart),
// 16 members each -> root counter -> release flag. ph = barrier index.
__device__ __forceinline__ void grid_barrier128(int* sb, int ph) {
  __syncthreads();
  if (threadIdx.x == 0) {
    int* base = sb + ph * 160;
    const int grp = blockIdx.x & 7;
    int v = __hip_atomic_fetch_add(base + grp * 16, 1, __ATOMIC_ACQ_REL, __HIP_MEMORY_SCOPE_AGENT);
    if (v == 15) {
      int r = __hip_atomic_fetch_add(base + 128, 1, __ATOMIC_ACQ_REL, __HIP_MEMORY_SCOPE_AGENT);
      if (r == 7)
        __hip_atomic_store(base + 144, 1, __ATOMIC_RELEASE, __HIP_MEMORY_SCOPE_AGENT);
    }
    while (!__hip_atomic_load(base + 144, __ATOMIC_RELAXED, __HIP_MEMORY_SCOPE_AGENT))
      __builtin_amdgcn_s_sleep(8);
    (void)__hip_atomic_load(base + 144, __ATOMIC_ACQUIRE, __HIP_MEMORY_SCOPE_AGENT);
  }
  __syncthreads();
}

// Tail kernel: 128 blocks (one per h). A-strip loaded once; lv3 (m=64),
// lv4 (m=32), lv5 (m=16) separated by hierarchical barriers; log-softmax
// output epilogue after the last barrier (block b owns 16 g-nodes).
__global__ __launch_bounds__(256, 2) void tail_kernel(
    const _Float16* __restrict__ V16, const float* __restrict__ W, const float* __restrict__ bb,
    _Float16* __restrict__ H16A, _Float16* __restrict__ H16B,
    float* __restrict__ Hgt, const float* __restrict__ Wout,
    const float* __restrict__ Wb, float* __restrict__ out, int* __restrict__ syncb)
{
  __shared__ _Float16 Ct[32 * 256];
  __shared__ float Wk[256];
  __shared__ float red[4][32];

  const int h = blockIdx.x;
  const int tid = threadIdx.x, lane = tid & 63, w = tid >> 6;
  const int lo16 = lane & 15, q = lane >> 4;
  const int nidx = tid & 31, oct = tid >> 5;
  char* cb = (char*)Ct;

  Wk[tid] = W[(size_t)tid * HID + h];

  const _Float16* Vh = V16 + (size_t)h * 65536;
  f16x8 af[4][8];
#pragma unroll
  for (int rf = 0; rf < 4; ++rf) {
    const int r = w * 64 + rf * 16 + lo16;
#pragma unroll
    for (int lc = 0; lc < 8; ++lc)
      af[rf][lc] = *(const f16x8*)(Vh + (size_t)r * 256 + lc * 32 + q * 8);
  }
  __syncthreads();
  f32x4 wk[4];
#pragma unroll
  for (int rf = 0; rf < 4; ++rf)
    wk[rf] = *(const f32x4*)&Wk[w * 64 + rf * 16 + q * 4];
  const float bh = bb[h];

#pragma unroll
  for (int lv = 3; lv < 6; ++lv) {
    const int m = 512 >> lv;
    const int lognpt = 5 - lv;
    const int sst = (1 << (lv + 2)) - 1;
    const _Float16* Hp = (lv & 1) ? H16B : H16A;   // lv3:B lv4:A lv5:B
    _Float16* Hn       = (lv & 1) ? H16A : H16B;
    const int ntiles = (m + 31) >> 5;

    for (int t = 0; t < ntiles; ++t) {
      const int nb = t * 32;
      int nn = m - nb; if (nn > 32) nn = 32;
      const int ncf = (nn + 15) >> 4;

      __syncthreads();
      if (nidx < nn) {
        unsigned int u[16];
#pragma unroll
        for (int half = 0; half < 2; ++half)
#pragma unroll
          for (int j = 0; j < 8; ++j)
            u[half * 8 + j] = *(const unsigned int*)(
                Hp + (size_t)(half * 64 + oct * 8 + j) * NW + 2 * (nb + nidx));
#pragma unroll
        for (int half = 0; half < 2; ++half) {
          union { f16x8 v; unsigned short s[8]; } a0, a1;
#pragma unroll
          for (int j = 0; j < 8; ++j) {
            a0.s[j] = (unsigned short)(u[half * 8 + j] & 0xffffu);
            a1.s[j] = (unsigned short)(u[half * 8 + j] >> 16);
          }
          *(f16x8*)(cb + cswz(nidx, half * 128 + oct * 16)) = a0.v;
          *(f16x8*)(cb + cswz(nidx, 256 + half * 128 + oct * 16)) = a1.v;
        }
      }
      __syncthreads();

      f32x4 acc[4][2];
#pragma unroll
      for (int rf = 0; rf < 4; ++rf)
#pragma unroll
        for (int cf = 0; cf < 2; ++cf) { f32x4 z = {0.f, 0.f, 0.f, 0.f}; acc[rf][cf] = z; }

#pragma unroll
      for (int lc = 0; lc < 8; ++lc) {
#pragma unroll
        for (int cf = 0; cf < 2; ++cf) {
          if (cf < ncf) {
            const int nl = cf * 16 + lo16;
            const f16x8 Bf = *(const f16x8*)(cb + cswz(nl, lc * 64 + q * 16));
#pragma unroll
            for (int rf = 0; rf < 4; ++rf)
              acc[rf][cf] = __builtin_amdgcn_mfma_f32_16x16x32_f16(af[rf][lc], Bf, acc[rf][cf], 0, 0, 0);
          }
        }
      }

      float pt[2];
#pragma unroll
      for (int cf = 0; cf < 2; ++cf) {
        pt[cf] = 0.f;
        if (cf < ncf) {
          const int nl = cf * 16 + lo16;
          float s = 0.f;
#pragma unroll
          for (int rf = 0; rf < 4; ++rf) {
            const int kb = w * 64 + rf * 16 + q * 4;
            const f16x4 cv = *(const f16x4*)(cb + cswz(nl, kb * 2));
            s += (float)cv[0] * (acc[rf][cf][0] + wk[rf][0])
               + (float)cv[1] * (acc[rf][cf][1] + wk[rf][1])
               + (float)cv[2] * (acc[rf][cf][2] + wk[rf][2])
               + (float)cv[3] * (acc[rf][cf][3] + wk[rf][3]);
          }
          pt[cf] = s;
        }
      }
#pragma unroll
      for (int cf = 0; cf < 2; ++cf) {
        pt[cf] += __shfl_xor(pt[cf], 16);
        pt[cf] += __shfl_xor(pt[cf], 32);
      }
      if (q == 0) {
#pragma unroll
        for (int cf = 0; cf < 2; ++cf)
          if (cf < ncf) red[w][cf * 16 + lo16] = pt[cf];
      }
      __syncthreads();
      if (tid < nn) {
        const float x = red[0][tid] + red[1][tid] + red[2][tid] + red[3][tid] + bh;
        const float tnh = tanhf(x);
        const int node = nb + tid;
        Hn[(size_t)h * NW + node] = (_Float16)tnh;
        const int tr = node >> lognpt, p = node & ((1 << lognpt) - 1);
        const int g = tr * NPT + tree_idx(p, sst);
        Hgt[(size_t)h * 2048 + g] = tnh;
      }
    }
    grid_barrier128(syncb, lv - 3);   // barriers 0,1,2 after lv3,lv4,lv5
  }

  // ---- output epilogue: block b owns nodes b*16 .. b*16+15 (2032 = 127*16)
  if (blockIdx.x < 127) {
    const int node = blockIdx.x * 16 + (tid >> 4);
    const int hs = tid & 15;
    float l0 = 0.f, l1 = 0.f, l2 = 0.f, l3 = 0.f, l4 = 0.f;
#pragma unroll
    for (int j = 0; j < 8; ++j) {
      const int hh = hs + j * 16;
      const float x = Hgt[(size_t)hh * 2048 + node];
      const float* wr = Wout + (size_t)hh * 5;
      l0 += x * wr[0]; l1 += x * wr[1]; l2 += x * wr[2];
      l3 += x * wr[3]; l4 += x * wr[4];
    }
#pragma unroll
    for (int d = 1; d < 16; d <<= 1) {
      l0 += __shfl_xor(l0, d); l1 += __shfl_xor(l1, d); l2 += __shfl_xor(l2, d);
      l3 += __shfl_xor(l3, d); l4 += __shfl_xor(l4, d);
    }
    if (hs == 0) {
      l0 += Wb[0]; l1 += Wb[1]; l2 += Wb[2]; l3 += Wb[3]; l4 += Wb[4];
      const float mm = fmaxf(fmaxf(fmaxf(l0, l1), fmaxf(l2, l3)), l4);
      const float ss = expf(l0 - mm) + expf(l1 - mm) + expf(l2 - mm)
                     + expf(l3 - mm) + expf(l4 - mm);
      const float lse = mm + logf(ss);
      float* o = out + (size_t)node * 5;
      o[0] = l0 - lse; o[1] = l1 - lse; o[2] = l2 - lse; o[3] = l3 - lse; o[4] = l4 - lse;
    }
  }
}

extern "C" void kernel_launch(void* const* d_in, const int* in_sizes, int n_in,
                              void* d_out, int out_size, void* d_ws, size_t ws_size,
                              hipStream_t stream) {
  const float* embed = (const float*)d_in[0];
  const float* V     = (const float*)d_in[1];
  const float* W     = (const float*)d_in[2];
  const float* b     = (const float*)d_in[3];
  const float* Wout  = (const float*)d_in[4];
  const float* Woutb = (const float*)d_in[5];
  const int* word_idx = (const int*)d_in[7];
  float* out = (float*)d_out;

  // ws: V16 | H16A | H16B | Hgt | sync
  char* wsb = (char*)d_ws;
  _Float16* V16  = (_Float16*)wsb;                      // 16777216
  _Float16* H16A = (_Float16*)(wsb + 16777216);         //   262144
  _Float16* H16B = (_Float16*)(wsb + 17039360);         //   262144
  float*    Hgt  = (float*)(wsb + 17301504);            //  1048576
  int*     syncb = (int*)(wsb + 18350080);              //     4096

  hipMemsetAsync(syncb, 0, 4096, stream);
  prep_kernel<<<1152, 256, 0, stream>>>(V, V16, embed, word_idx, H16A, Hgt);

  level_kernel<4><<<512, 256, 0, stream>>>(V16, W, b, H16A, H16B, Hgt, 0); // m=512
  level_kernel<4><<<512, 256, 0, stream>>>(V16, W, b, H16B, H16A, Hgt, 1); // m=256
  level_kernel<2><<<256, 256, 0, stream>>>(V16, W, b, H16A, H16B, Hgt, 2); // m=128

  tail_kernel<<<128, 256, 0, stream>>>(V16, W, b, H16A, H16B, Hgt, Wout, Woutb, out, syncb);
}